// Round 9
// baseline (199.353 us; speedup 1.0000x reference)
//
#include <hip/hip_runtime.h>
#include <hip/hip_bf16.h>

#define L_SEQ 2048
#define D_HEAD 64
#define NHEADS 64   // B*H
#define QSCALE (0.125f * 1.44269504088896340736f)  // 1/sqrt(64) * log2(e)

typedef __attribute__((ext_vector_type(8))) __bf16 bf16x8;
typedef __attribute__((ext_vector_type(16))) float f32x16;

// [rows][64] bf16 tile (128B rows), XOR-swizzled (G4).
__device__ __forceinline__ int swz(int row, int col) {
    int off = (row << 7) | (col << 1);
    return off ^ ((row & 7) << 4);
}
__device__ __forceinline__ bf16x8 read_frag(const char* lds, int row, int col) {
    return *reinterpret_cast<const bf16x8*>(lds + swz(row, col));
}
__device__ __forceinline__ void pack_write(char* lds, int row, int c4, float4 v,
                                           float4 sc) {
    union { __bf16 h[4]; unsigned long long u; } pk;
    pk.h[0] = (__bf16)(v.x * sc.x);
    pk.h[1] = (__bf16)(v.y * sc.y);
    pk.h[2] = (__bf16)(v.z * sc.z);
    pk.h[3] = (__bf16)(v.w * sc.w);
    *reinterpret_cast<unsigned long long*>(lds + swz(row, c4)) = pk.u;
}

__device__ __forceinline__ unsigned cvt_pk_bf16(float lo, float hi) {
    unsigned r;
    asm("v_cvt_pk_bf16_f32 %0, %1, %2" : "=v"(r) : "v"(lo), "v"(hi));
    return r;
}

// -------- Pass 1: invl[bh][q] = 1 / sum_k exp2(QSCALE*(Q.K)) ----------------
// q-tile 128; 4 waves, wave w owns q-rows [w*32, w*32+32) (qfrag in regs).
// K streamed k-step 128 double-buffered (16 steps). Grid 1024 @ 4/CU = clean.
__global__ __launch_bounds__(256, 4) void attn_pass1(const float* __restrict__ Q,
                                                     const float* __restrict__ K,
                                                     float* __restrict__ invl) {
    __shared__ __align__(16) char lds[32768];   // 2 x 16KB K[128][64] dbuf
    __shared__ float red[128];

    int bid = blockIdx.x;
    int sb = (bid & 7) * 128 + (bid >> 3);   // bijective XCD swizzle (1024 = 8*128)
    int bh = sb >> 4;
    int q0 = (sb & 15) << 7;
    const float* Qh = Q + (size_t)bh * L_SEQ * D_HEAD + (size_t)q0 * D_HEAD;
    const float* Kh = K + (size_t)bh * L_SEQ * D_HEAD;

    int t = threadIdx.x, lane = t & 63, w = t >> 6;
    int hl = lane >> 5, l31 = lane & 31;
    int r0 = t >> 4;          // 0..15
    int c4 = (t & 15) << 2;

    // stage Q[128][64] into buf0, read qfrag (this wave's 32 q-rows), free it
    {
        float4 qs = make_float4(QSCALE, QSCALE, QSCALE, QSCALE);
#pragma unroll
        for (int i = 0; i < 8; ++i) {
            float4 v = *reinterpret_cast<const float4*>(Qh + (size_t)(r0 + i * 16) * D_HEAD + c4);
            pack_write(lds, r0 + i * 16, c4, v, qs);
        }
    }
    __syncthreads();
    bf16x8 qfrag[4];
#pragma unroll
    for (int m = 0; m < 4; ++m)
        qfrag[m] = read_frag(lds, w * 32 + l31, m * 16 + hl * 8);
    __syncthreads();
    // stage K tile 0 into buf0
    {
        float4 one = make_float4(1.f, 1.f, 1.f, 1.f);
#pragma unroll
        for (int i = 0; i < 8; ++i) {
            float4 v = *reinterpret_cast<const float4*>(Kh + (size_t)(r0 + i * 16) * D_HEAD + c4);
            pack_write(lds, r0 + i * 16, c4, v, one);
        }
    }
    __syncthreads();

    float lsum[16];
#pragma unroll
    for (int r = 0; r < 16; ++r) lsum[r] = 0.f;

    for (int k0 = 0; k0 < L_SEQ; k0 += 128) {
        int c = (k0 >> 7) & 1;
        const char* kcur = lds + (c ? 16384 : 0);
        char* knext = lds + (c ? 0 : 16384);

        int nk0 = (k0 + 128) & (L_SEQ - 1);
        float4 kreg[4];
#pragma unroll
        for (int i = 0; i < 4; ++i)
            kreg[i] = *reinterpret_cast<const float4*>(Kh + (size_t)(nk0 + r0 + i * 16) * D_HEAD + c4);

#pragma unroll
        for (int kb = 0; kb < 4; ++kb) {
            bf16x8 kfr[4];
#pragma unroll
            for (int m = 0; m < 4; ++m)
                kfr[m] = read_frag(kcur, kb * 32 + l31, m * 16 + hl * 8);

            f32x16 s;
#pragma unroll
            for (int r = 0; r < 16; ++r) s[r] = 0.f;
            __builtin_amdgcn_s_setprio(1);
#pragma unroll
            for (int m = 0; m < 4; ++m)
                s = __builtin_amdgcn_mfma_f32_32x32x16_bf16(qfrag[m], kfr[m], s, 0, 0, 0);
            __builtin_amdgcn_s_setprio(0);
#pragma unroll
            for (int r = 0; r < 16; ++r)
                lsum[r] += __builtin_amdgcn_exp2f(s[r]);

            if (kb == 1) {
                // write prefetched half, issue second half loads
                float4 one = make_float4(1.f, 1.f, 1.f, 1.f);
#pragma unroll
                for (int i = 0; i < 4; ++i)
                    pack_write(knext, r0 + i * 16, c4, kreg[i], one);
#pragma unroll
                for (int i = 0; i < 4; ++i)
                    kreg[i] = *reinterpret_cast<const float4*>(Kh + (size_t)(nk0 + r0 + (i + 4) * 16) * D_HEAD + c4);
            }
        }
        {
            float4 one = make_float4(1.f, 1.f, 1.f, 1.f);
#pragma unroll
            for (int i = 0; i < 4; ++i)
                pack_write(knext, r0 + (i + 4) * 16, c4, kreg[i], one);
        }
        __syncthreads();   // single barrier per 128-k step
    }

    // reduce over the 32 k-lanes; each wave owns distinct q-rows
#pragma unroll
    for (int r = 0; r < 16; ++r) {
        float v = lsum[r];
        v += __shfl_xor(v, 1);
        v += __shfl_xor(v, 2);
        v += __shfl_xor(v, 4);
        v += __shfl_xor(v, 8);
        v += __shfl_xor(v, 16);
        lsum[r] = v;
    }
    if (l31 == 0) {
#pragma unroll
        for (int r = 0; r < 16; ++r)
            red[w * 32 + (r & 3) + 8 * (r >> 2) + 4 * hl] = lsum[r];
    }
    __syncthreads();
    if (t < 128)
        invl[(size_t)bh * L_SEQ + q0 + t] = 1.0f / red[t];
}

// -------- Pass 2: Out[d, k-tile] = sum_q (V[d,q]*invl[q]) * exp2(s[q,k]) ----
// 256 thr / 4 waves; k-tile 256, wave owns 64 k-cols: kfrag[2][4] in regs,
// acc[2][2]. Per qq: 8 LDS frag reads -> 16 MFMA (1:2 read:MFMA). Q/V dbuf,
// one barrier per 64-q step. Grid 512 @ 2 blocks/CU = clean single batch.
__global__ __launch_bounds__(256, 2) void attn_pass2(const float* __restrict__ Q,
                                                     const float* __restrict__ K,
                                                     const float* __restrict__ V,
                                                     const float* __restrict__ invl,
                                                     float* __restrict__ out) {
    __shared__ __align__(16) char lds[65536];
    // [0,32K) K[256][64]; Q bufs @32768/40960; V bufs @49152/57344 (8KB each)

    int bid = blockIdx.x;
    int sb = (bid & 7) * 64 + (bid >> 3);    // bijective XCD swizzle (512 = 8*64)
    int bh = sb >> 3;
    int k0 = (sb & 7) << 8;
    const float* Qh = Q + (size_t)bh * L_SEQ * D_HEAD;
    const float* Kh = K + (size_t)bh * L_SEQ * D_HEAD + (size_t)k0 * D_HEAD;
    const float* Vh = V + (size_t)bh * D_HEAD * L_SEQ;
    const float* il = invl + (size_t)bh * L_SEQ;
    float* Oh = out + (size_t)bh * D_HEAD * L_SEQ;

    int t = threadIdx.x, lane = t & 63, w = t >> 6;    // w 0..3
    int hl = lane >> 5, l31 = lane & 31;
    int r0 = t >> 4;          // 0..15
    int c4 = (t & 15) << 2;

    // prologue A: stage K[256][64] (batches of 4 rows/thread), read kfrags
    {
        float4 one = make_float4(1.f, 1.f, 1.f, 1.f);
#pragma unroll
        for (int i = 0; i < 16; i += 4) {
            float4 kr[4];
#pragma unroll
            for (int j = 0; j < 4; ++j)
                kr[j] = *reinterpret_cast<const float4*>(Kh + (size_t)(r0 + (i + j) * 16) * D_HEAD + c4);
#pragma unroll
            for (int j = 0; j < 4; ++j)
                pack_write(lds, r0 + (i + j) * 16, c4, kr[j], one);
        }
    }
    __syncthreads();
    bf16x8 kfrag[2][4];
#pragma unroll
    for (int kb = 0; kb < 2; ++kb)
#pragma unroll
        for (int m = 0; m < 4; ++m)
            kfrag[kb][m] = read_frag(lds, w * 64 + kb * 32 + l31, m * 16 + hl * 8);

    // prologue B: stage Q0 / V0 (V scaled by invl; V cols = q)
    {
        float4 qs = make_float4(QSCALE, QSCALE, QSCALE, QSCALE);
        float4 iv = *reinterpret_cast<const float4*>(il + c4);
#pragma unroll
        for (int i = 0; i < 4; ++i) {
            float4 qv = *reinterpret_cast<const float4*>(Qh + (size_t)(r0 + i * 16) * D_HEAD + c4);
            float4 vv = *reinterpret_cast<const float4*>(Vh + (size_t)(r0 + i * 16) * L_SEQ + c4);
            pack_write(lds + 32768, r0 + i * 16, c4, qv, qs);
            pack_write(lds + 49152, r0 + i * 16, c4, vv, iv);
        }
    }
    __syncthreads();

    f32x16 acc[2][2];
#pragma unroll
    for (int db = 0; db < 2; ++db)
#pragma unroll
        for (int kb = 0; kb < 2; ++kb)
#pragma unroll
            for (int r = 0; r < 16; ++r) acc[db][kb][r] = 0.f;

    for (int q0 = 0; q0 < L_SEQ; q0 += 64) {
        int c = (q0 >> 6) & 1;
        const char* qcur = lds + 32768 + (c ? 8192 : 0);
        const char* vcur = lds + 49152 + (c ? 8192 : 0);
        char* qnext = lds + 32768 + (c ? 0 : 8192);
        char* vnext = lds + 49152 + (c ? 0 : 8192);

        // issue next-tile loads (wrapped on last iter)
        int nq0 = (q0 + 64) & (L_SEQ - 1);
        float4 qreg[4], vreg[4];
#pragma unroll
        for (int i = 0; i < 4; ++i) {
            qreg[i] = *reinterpret_cast<const float4*>(Qh + (size_t)(nq0 + r0 + i * 16) * D_HEAD + c4);
            vreg[i] = *reinterpret_cast<const float4*>(Vh + (size_t)(r0 + i * 16) * L_SEQ + nq0 + c4);
        }
        float4 ivn = *reinterpret_cast<const float4*>(il + nq0 + c4);

#pragma unroll
        for (int qq = 0; qq < 2; ++qq) {
            // S = Q.K^T : 4 Q reads feed both kb chains (8 MFMA)
            f32x16 s[2];
#pragma unroll
            for (int kb = 0; kb < 2; ++kb)
#pragma unroll
                for (int r = 0; r < 16; ++r) s[kb][r] = 0.f;

            __builtin_amdgcn_s_setprio(1);
#pragma unroll
            for (int m = 0; m < 4; ++m) {
                bf16x8 afr = read_frag(qcur, qq * 32 + l31, m * 16 + hl * 8);
                s[0] = __builtin_amdgcn_mfma_f32_32x32x16_bf16(afr, kfrag[0][m], s[0], 0, 0, 0);
                s[1] = __builtin_amdgcn_mfma_f32_32x32x16_bf16(afr, kfrag[1][m], s[1], 0, 0, 0);
            }
            __builtin_amdgcn_s_setprio(0);

            // P = exp2(s) -> bf16 frag words in-register
            bf16x8 pfrag[2][2];
#pragma unroll
            for (int kb = 0; kb < 2; ++kb) {
                unsigned wA[4], wB[4];
#pragma unroll
                for (int g = 0; g < 4; ++g) {
                    wA[g] = cvt_pk_bf16(__builtin_amdgcn_exp2f(s[kb][4 * g + 0]),
                                        __builtin_amdgcn_exp2f(s[kb][4 * g + 1]));
                    wB[g] = cvt_pk_bf16(__builtin_amdgcn_exp2f(s[kb][4 * g + 2]),
                                        __builtin_amdgcn_exp2f(s[kb][4 * g + 3]));
                }
#pragma unroll
                for (int mm = 0; mm < 2; ++mm) {
                    unsigned a0 = wA[2 * mm], b0 = wA[2 * mm + 1];
                    unsigned a1 = wB[2 * mm], b1 = wB[2 * mm + 1];
                    asm volatile("v_permlane32_swap_b32 %0, %1" : "+v"(a0), "+v"(b0));
                    asm volatile("v_permlane32_swap_b32 %0, %1" : "+v"(a1), "+v"(b1));
                    union { unsigned u[4]; bf16x8 v; } pk;
                    pk.u[0] = a0;
                    pk.u[1] = a1;
                    pk.u[2] = b0;
                    pk.u[3] = b1;
                    pfrag[kb][mm] = pk.v;
                }
            }

            // PV: 4 V reads feed 8 MFMA (4 independent acc chains)
            __builtin_amdgcn_s_setprio(1);
#pragma unroll
            for (int mm = 0; mm < 2; ++mm)
#pragma unroll
                for (int db = 0; db < 2; ++db) {
                    bf16x8 vfr = read_frag(vcur, db * 32 + l31, qq * 32 + mm * 16 + hl * 8);
#pragma unroll
                    for (int kb = 0; kb < 2; ++kb)
                        acc[db][kb] = __builtin_amdgcn_mfma_f32_32x32x16_bf16(
                            vfr, pfrag[kb][mm], acc[db][kb], 0, 0, 0);
                }
            __builtin_amdgcn_s_setprio(0);
        }

        // write next Q/V, flip
        {
            float4 qs = make_float4(QSCALE, QSCALE, QSCALE, QSCALE);
#pragma unroll
            for (int i = 0; i < 4; ++i) {
                pack_write(qnext, r0 + i * 16, c4, qreg[i], qs);
                pack_write(vnext, r0 + i * 16, c4, vreg[i], ivn);
            }
        }
        __syncthreads();   // single barrier per 64-q step
    }

#pragma unroll
    for (int db = 0; db < 2; ++db)
#pragma unroll
        for (int kb = 0; kb < 2; ++kb)
#pragma unroll
            for (int r = 0; r < 16; ++r) {
                int d = db * 32 + (r & 3) + 8 * (r >> 2) + 4 * hl;
                int k = k0 + w * 64 + kb * 32 + l31;
                Oh[(size_t)d * L_SEQ + k] = acc[db][kb][r];
            }
}

extern "C" void kernel_launch(void* const* d_in, const int* in_sizes, int n_in,
                              void* d_out, int out_size, void* d_ws, size_t ws_size,
                              hipStream_t stream) {
    const float* Q = (const float*)d_in[0];
    const float* K = (const float*)d_in[1];
    const float* V = (const float*)d_in[2];
    float* invl = (float*)d_ws;          // NHEADS * L_SEQ floats = 512 KB
    float* out = (float*)d_out;

    attn_pass1<<<dim3(NHEADS * (L_SEQ / 128)), dim3(256), 0, stream>>>(Q, K, invl);
    attn_pass2<<<dim3(NHEADS * (L_SEQ / 256)), dim3(256), 0, stream>>>(Q, K, V, invl, out);
}

// Round 10
// 142.536 us; speedup vs baseline: 1.3986x; 1.3986x over previous
//
#include <hip/hip_runtime.h>
#include <hip/hip_bf16.h>

#define L_SEQ 2048
#define D_HEAD 64
#define NHEADS 64   // B*H
#define QSCALE (0.125f * 1.44269504088896340736f)  // 1/sqrt(64) * log2(e)

typedef __attribute__((ext_vector_type(8))) __bf16 bf16x8;
typedef __attribute__((ext_vector_type(16))) float f32x16;

// [rows][64] bf16 tile (128B rows), XOR-swizzled (G4).
__device__ __forceinline__ int swz(int row, int col) {
    int off = (row << 7) | (col << 1);
    return off ^ ((row & 7) << 4);
}
__device__ __forceinline__ bf16x8 read_frag(const char* lds, int row, int col) {
    return *reinterpret_cast<const bf16x8*>(lds + swz(row, col));
}
__device__ __forceinline__ void pack_write(char* lds, int row, int c4, float4 v,
                                           float4 sc) {
    union { __bf16 h[4]; unsigned long long u; } pk;
    pk.h[0] = (__bf16)(v.x * sc.x);
    pk.h[1] = (__bf16)(v.y * sc.y);
    pk.h[2] = (__bf16)(v.z * sc.z);
    pk.h[3] = (__bf16)(v.w * sc.w);
    *reinterpret_cast<unsigned long long*>(lds + swz(row, c4)) = pk.u;
}

__device__ __forceinline__ unsigned cvt_pk_bf16(float lo, float hi) {
    unsigned r;
    asm("v_cvt_pk_bf16_f32 %0, %1, %2" : "=v"(r) : "v"(lo), "v"(hi));
    return r;
}

// -------- Pass 1: invl[bh][q] = 1 / sum_k exp2(QSCALE*(Q.K)) ----------------
// Round-8 version (proven ~45-48 us): q-tile 128, 4 waves = wq2 x wk2
// (wave: 64 q-rows x 32 k-cols, qfrag[2][4] in regs -> 4 reads : 8 MFMA),
// k-step 64 double-buffered, one barrier/step. Grid 1024 @ 4/CU = clean.
__global__ __launch_bounds__(256, 4) void attn_pass1(const float* __restrict__ Q,
                                                     const float* __restrict__ K,
                                                     float* __restrict__ invl) {
    __shared__ __align__(16) char lds[16384];   // Q stage, then 2 x 8KB K dbuf
    __shared__ float red[2][128];

    int bid = blockIdx.x;
    int sb = (bid & 7) * 128 + (bid >> 3);   // bijective XCD swizzle (1024 = 8*128)
    int bh = sb >> 4;
    int q0 = (sb & 15) << 7;
    const float* Qh = Q + (size_t)bh * L_SEQ * D_HEAD + (size_t)q0 * D_HEAD;
    const float* Kh = K + (size_t)bh * L_SEQ * D_HEAD;

    int t = threadIdx.x, lane = t & 63, w = t >> 6;
    int wq = w >> 1, wk = w & 1;
    int hl = lane >> 5, l31 = lane & 31;
    int r0 = t >> 4;          // 0..15
    int c4 = (t & 15) << 2;

    // stage Q[128][64] (rows 0..127 across the 16KB region)
    {
        float4 qs = make_float4(QSCALE, QSCALE, QSCALE, QSCALE);
#pragma unroll
        for (int i = 0; i < 8; ++i) {
            float4 v = *reinterpret_cast<const float4*>(Qh + (size_t)(r0 + i * 16) * D_HEAD + c4);
            pack_write(lds, r0 + i * 16, c4, v, qs);
        }
    }
    __syncthreads();
    bf16x8 qfrag[2][4];
#pragma unroll
    for (int qb = 0; qb < 2; ++qb)
#pragma unroll
        for (int m = 0; m < 4; ++m)
            qfrag[qb][m] = read_frag(lds, wq * 64 + qb * 32 + l31, m * 16 + hl * 8);
    __syncthreads();
    // stage K tile 0 into buf0
    {
        float4 one = make_float4(1.f, 1.f, 1.f, 1.f);
#pragma unroll
        for (int i = 0; i < 4; ++i) {
            float4 v = *reinterpret_cast<const float4*>(Kh + (size_t)(r0 + i * 16) * D_HEAD + c4);
            pack_write(lds, r0 + i * 16, c4, v, one);
        }
    }
    __syncthreads();

    float lsum[2][16];
#pragma unroll
    for (int qb = 0; qb < 2; ++qb)
#pragma unroll
        for (int r = 0; r < 16; ++r) lsum[qb][r] = 0.f;

    for (int k0 = 0; k0 < L_SEQ; k0 += 64) {
        int c = (k0 >> 6) & 1;
        const char* kcur = lds + (c ? 8192 : 0);
        char* knext = lds + (c ? 0 : 8192);

        int nk0 = (k0 + 64) & (L_SEQ - 1);
        float4 kreg[4];
#pragma unroll
        for (int i = 0; i < 4; ++i)
            kreg[i] = *reinterpret_cast<const float4*>(Kh + (size_t)(nk0 + r0 + i * 16) * D_HEAD + c4);

        bf16x8 kfr[4];
#pragma unroll
        for (int m = 0; m < 4; ++m)
            kfr[m] = read_frag(kcur, wk * 32 + l31, m * 16 + hl * 8);

        __builtin_amdgcn_s_setprio(1);
#pragma unroll
        for (int qb = 0; qb < 2; ++qb) {
            f32x16 s;
#pragma unroll
            for (int r = 0; r < 16; ++r) s[r] = 0.f;
#pragma unroll
            for (int m = 0; m < 4; ++m)
                s = __builtin_amdgcn_mfma_f32_32x32x16_bf16(qfrag[qb][m], kfr[m], s, 0, 0, 0);
#pragma unroll
            for (int r = 0; r < 16; ++r)
                lsum[qb][r] += __builtin_amdgcn_exp2f(s[r]);
        }
        __builtin_amdgcn_s_setprio(0);

        {
            float4 one = make_float4(1.f, 1.f, 1.f, 1.f);
#pragma unroll
            for (int i = 0; i < 4; ++i)
                pack_write(knext, r0 + i * 16, c4, kreg[i], one);
        }
        __syncthreads();   // single barrier per step (double-buffered)
    }

    // reduce over this wave's 32 k-lanes
#pragma unroll
    for (int qb = 0; qb < 2; ++qb)
#pragma unroll
        for (int r = 0; r < 16; ++r) {
            float v = lsum[qb][r];
            v += __shfl_xor(v, 1);
            v += __shfl_xor(v, 2);
            v += __shfl_xor(v, 4);
            v += __shfl_xor(v, 8);
            v += __shfl_xor(v, 16);
            lsum[qb][r] = v;
        }
    if (l31 == 0) {
#pragma unroll
        for (int qb = 0; qb < 2; ++qb)
#pragma unroll
            for (int r = 0; r < 16; ++r)
                red[wk][wq * 64 + qb * 32 + (r & 3) + 8 * (r >> 2) + 4 * hl] = lsum[qb][r];
    }
    __syncthreads();
    if (t < 128) {
        float ssum = red[0][t] + red[1][t];
        invl[(size_t)bh * L_SEQ + q0 + t] = 1.0f / ssum;
    }
}

// -------- Pass 2: Out[d, k-tile] = sum_q (V[d,q]*invl[q]) * exp2(s[q,k]) ----
// Round-9 version (proven ~60 us): 256 thr / 4 waves; k-tile 256, wave owns
// 64 k-cols: kfrag[2][4] in regs, acc[2][2]. Per qq: 8 LDS frag reads -> 16
// MFMA (1:2). Q/V dbuf, one barrier per 64-q step. Grid 512 @ 2/CU = clean.
__global__ __launch_bounds__(256, 2) void attn_pass2(const float* __restrict__ Q,
                                                     const float* __restrict__ K,
                                                     const float* __restrict__ V,
                                                     const float* __restrict__ invl,
                                                     float* __restrict__ out) {
    __shared__ __align__(16) char lds[65536];
    // [0,32K) K[256][64]; Q bufs @32768/40960; V bufs @49152/57344 (8KB each)

    int bid = blockIdx.x;
    int sb = (bid & 7) * 64 + (bid >> 3);    // bijective XCD swizzle (512 = 8*64)
    int bh = sb >> 3;
    int k0 = (sb & 7) << 8;
    const float* Qh = Q + (size_t)bh * L_SEQ * D_HEAD;
    const float* Kh = K + (size_t)bh * L_SEQ * D_HEAD + (size_t)k0 * D_HEAD;
    const float* Vh = V + (size_t)bh * D_HEAD * L_SEQ;
    const float* il = invl + (size_t)bh * L_SEQ;
    float* Oh = out + (size_t)bh * D_HEAD * L_SEQ;

    int t = threadIdx.x, lane = t & 63, w = t >> 6;    // w 0..3
    int hl = lane >> 5, l31 = lane & 31;
    int r0 = t >> 4;          // 0..15
    int c4 = (t & 15) << 2;

    // prologue A: stage K[256][64] (batches of 4 rows/thread), read kfrags
    {
        float4 one = make_float4(1.f, 1.f, 1.f, 1.f);
#pragma unroll
        for (int i = 0; i < 16; i += 4) {
            float4 kr[4];
#pragma unroll
            for (int j = 0; j < 4; ++j)
                kr[j] = *reinterpret_cast<const float4*>(Kh + (size_t)(r0 + (i + j) * 16) * D_HEAD + c4);
#pragma unroll
            for (int j = 0; j < 4; ++j)
                pack_write(lds, r0 + (i + j) * 16, c4, kr[j], one);
        }
    }
    __syncthreads();
    bf16x8 kfrag[2][4];
#pragma unroll
    for (int kb = 0; kb < 2; ++kb)
#pragma unroll
        for (int m = 0; m < 4; ++m)
            kfrag[kb][m] = read_frag(lds, w * 64 + kb * 32 + l31, m * 16 + hl * 8);

    // prologue B: stage Q0 / V0 (V scaled by invl; V cols = q)
    {
        float4 qs = make_float4(QSCALE, QSCALE, QSCALE, QSCALE);
        float4 iv = *reinterpret_cast<const float4*>(il + c4);
#pragma unroll
        for (int i = 0; i < 4; ++i) {
            float4 qv = *reinterpret_cast<const float4*>(Qh + (size_t)(r0 + i * 16) * D_HEAD + c4);
            float4 vv = *reinterpret_cast<const float4*>(Vh + (size_t)(r0 + i * 16) * L_SEQ + c4);
            pack_write(lds + 32768, r0 + i * 16, c4, qv, qs);
            pack_write(lds + 49152, r0 + i * 16, c4, vv, iv);
        }
    }
    __syncthreads();

    f32x16 acc[2][2];
#pragma unroll
    for (int db = 0; db < 2; ++db)
#pragma unroll
        for (int kb = 0; kb < 2; ++kb)
#pragma unroll
            for (int r = 0; r < 16; ++r) acc[db][kb][r] = 0.f;

    for (int q0 = 0; q0 < L_SEQ; q0 += 64) {
        int c = (q0 >> 6) & 1;
        const char* qcur = lds + 32768 + (c ? 8192 : 0);
        const char* vcur = lds + 49152 + (c ? 8192 : 0);
        char* qnext = lds + 32768 + (c ? 0 : 8192);
        char* vnext = lds + 49152 + (c ? 0 : 8192);

        // issue next-tile loads (wrapped on last iter)
        int nq0 = (q0 + 64) & (L_SEQ - 1);
        float4 qreg[4], vreg[4];
#pragma unroll
        for (int i = 0; i < 4; ++i) {
            qreg[i] = *reinterpret_cast<const float4*>(Qh + (size_t)(nq0 + r0 + i * 16) * D_HEAD + c4);
            vreg[i] = *reinterpret_cast<const float4*>(Vh + (size_t)(r0 + i * 16) * L_SEQ + nq0 + c4);
        }
        float4 ivn = *reinterpret_cast<const float4*>(il + nq0 + c4);

#pragma unroll
        for (int qq = 0; qq < 2; ++qq) {
            // S = Q.K^T : 4 Q reads feed both kb chains (8 MFMA)
            f32x16 s[2];
#pragma unroll
            for (int kb = 0; kb < 2; ++kb)
#pragma unroll
                for (int r = 0; r < 16; ++r) s[kb][r] = 0.f;

            __builtin_amdgcn_s_setprio(1);
#pragma unroll
            for (int m = 0; m < 4; ++m) {
                bf16x8 afr = read_frag(qcur, qq * 32 + l31, m * 16 + hl * 8);
                s[0] = __builtin_amdgcn_mfma_f32_32x32x16_bf16(afr, kfrag[0][m], s[0], 0, 0, 0);
                s[1] = __builtin_amdgcn_mfma_f32_32x32x16_bf16(afr, kfrag[1][m], s[1], 0, 0, 0);
            }
            __builtin_amdgcn_s_setprio(0);

            // P = exp2(s) -> bf16 frag words in-register
            bf16x8 pfrag[2][2];
#pragma unroll
            for (int kb = 0; kb < 2; ++kb) {
                unsigned wA[4], wB[4];
#pragma unroll
                for (int g = 0; g < 4; ++g) {
                    wA[g] = cvt_pk_bf16(__builtin_amdgcn_exp2f(s[kb][4 * g + 0]),
                                        __builtin_amdgcn_exp2f(s[kb][4 * g + 1]));
                    wB[g] = cvt_pk_bf16(__builtin_amdgcn_exp2f(s[kb][4 * g + 2]),
                                        __builtin_amdgcn_exp2f(s[kb][4 * g + 3]));
                }
#pragma unroll
                for (int mm = 0; mm < 2; ++mm) {
                    unsigned a0 = wA[2 * mm], b0 = wA[2 * mm + 1];
                    unsigned a1 = wB[2 * mm], b1 = wB[2 * mm + 1];
                    asm volatile("v_permlane32_swap_b32 %0, %1" : "+v"(a0), "+v"(b0));
                    asm volatile("v_permlane32_swap_b32 %0, %1" : "+v"(a1), "+v"(b1));
                    union { unsigned u[4]; bf16x8 v; } pk;
                    pk.u[0] = a0;
                    pk.u[1] = a1;
                    pk.u[2] = b0;
                    pk.u[3] = b1;
                    pfrag[kb][mm] = pk.v;
                }
            }

            // PV: 4 V reads feed 8 MFMA (4 independent acc chains)
            __builtin_amdgcn_s_setprio(1);
#pragma unroll
            for (int mm = 0; mm < 2; ++mm)
#pragma unroll
                for (int db = 0; db < 2; ++db) {
                    bf16x8 vfr = read_frag(vcur, db * 32 + l31, qq * 32 + mm * 16 + hl * 8);
#pragma unroll
                    for (int kb = 0; kb < 2; ++kb)
                        acc[db][kb] = __builtin_amdgcn_mfma_f32_32x32x16_bf16(
                            vfr, pfrag[kb][mm], acc[db][kb], 0, 0, 0);
                }
            __builtin_amdgcn_s_setprio(0);
        }

        // write next Q/V, flip
        {
            float4 qs = make_float4(QSCALE, QSCALE, QSCALE, QSCALE);
#pragma unroll
            for (int i = 0; i < 4; ++i) {
                pack_write(qnext, r0 + i * 16, c4, qreg[i], qs);
                pack_write(vnext, r0 + i * 16, c4, vreg[i], ivn);
            }
        }
        __syncthreads();   // single barrier per 64-q step
    }

#pragma unroll
    for (int db = 0; db < 2; ++db)
#pragma unroll
        for (int kb = 0; kb < 2; ++kb)
#pragma unroll
            for (int r = 0; r < 16; ++r) {
                int d = db * 32 + (r & 3) + 8 * (r >> 2) + 4 * hl;
                int k = k0 + w * 64 + kb * 32 + l31;
                Oh[(size_t)d * L_SEQ + k] = acc[db][kb][r];
            }
}

extern "C" void kernel_launch(void* const* d_in, const int* in_sizes, int n_in,
                              void* d_out, int out_size, void* d_ws, size_t ws_size,
                              hipStream_t stream) {
    const float* Q = (const float*)d_in[0];
    const float* K = (const float*)d_in[1];
    const float* V = (const float*)d_in[2];
    float* invl = (float*)d_ws;          // NHEADS * L_SEQ floats = 512 KB
    float* out = (float*)d_out;

    attn_pass1<<<dim3(NHEADS * (L_SEQ / 128)), dim3(256), 0, stream>>>(Q, K, invl);
    attn_pass2<<<dim3(NHEADS * (L_SEQ / 256)), dim3(256), 0, stream>>>(Q, K, V, invl, out);
}